// Round 3
// baseline (269.883 us; speedup 1.0000x reference)
//
#include <hip/hip_runtime.h>
#include <math.h>

#define NSP 4096   // H*W
#define CC  128    // channels
#define CIC 64     // inter channels
#define NB  4      // batch
#define LOG2E 1.4426950408889634f

typedef unsigned short u16;
typedef short s8bf __attribute__((ext_vector_type(8)));
typedef float f32x4 __attribute__((ext_vector_type(4)));

#define MFMA(a, b, c) __builtin_amdgcn_mfma_f32_16x16x32_bf16(a, b, c, 0, 0, 0)

// workspace byte offsets
#define WSB_PB    0                               // bf16 [B][128][NSP] (g:0-63, theta*log2e:64-127)
#define WSB_PH    (NB * 128 * NSP * 2)            // bf16 [B][NSP][64] phi token-major
#define WSB_Y     (WSB_PH + NB * NSP * CIC * 2)   // f32 [B][64][NSP]
#define WSB_SUMS  (WSB_Y + NB * CIC * NSP * 4)    // f32 [2][128] (sum, sumsq)

__device__ __forceinline__ u16 f2bf(float f) {
    union { float f; unsigned u; } v; v.f = f;
    unsigned r = v.u + 0x7fffu + ((v.u >> 16) & 1u);
    return (u16)(r >> 16);
}

// -------------------- Kernel 1: fused 1x1 projections ---------------------------
// g, theta (pre-scaled by log2e) -> bf16 channel-major; phi -> bf16 token-major.
__global__ __launch_bounds__(256) void proj_kernel(
    const float* __restrict__ x,
    const float* __restrict__ g_w, const float* __restrict__ g_b,
    const float* __restrict__ t_w, const float* __restrict__ t_b,
    const float* __restrict__ p_w, const float* __restrict__ p_b,
    u16* __restrict__ PB, u16* __restrict__ ph_tm)
{
    __shared__ float Wt[CC][196];
    __shared__ float Xs[CC][68];
    __shared__ u16 Tr[64][72];

    const int b   = blockIdx.y;
    const int n0  = blockIdx.x * 64;
    const int tid = threadIdx.x;
    const int nl  = tid & 63;
    const int og  = tid >> 6;
    const int ob  = og * 48;

    for (int j = 0; j < 32; ++j) {
        int idx = tid + (j << 8);
        int o = idx >> 7, c = idx & 127;
        Wt[c][o]       = g_w[idx];
        Wt[c][64 + o]  = t_w[idx];
        Wt[c][128 + o] = p_w[idx];
    }
    const float* xb = x + (size_t)b * CC * NSP + n0;
    for (int k = 0; k < 8; ++k) {
        int fi = tid + (k << 8);
        int c = fi >> 4, q = (fi & 15) << 2;
        *(float4*)&Xs[c][q] = *(const float4*)(xb + (size_t)c * NSP + q);
    }
    __syncthreads();

    float acc[48];
    #pragma unroll
    for (int j = 0; j < 48; ++j) {
        int o = ob + j;
        acc[j] = (o < 64) ? g_b[o] : (o < 128) ? t_b[o - 64] : p_b[o - 128];
    }

    for (int c = 0; c < CC; ++c) {
        float xv = Xs[c][nl];
        const float4* wr = (const float4*)&Wt[c][ob];
        #pragma unroll
        for (int j4 = 0; j4 < 12; ++j4) {
            float4 w4 = wr[j4];
            acc[j4 * 4 + 0] += w4.x * xv;
            acc[j4 * 4 + 1] += w4.y * xv;
            acc[j4 * 4 + 2] += w4.z * xv;
            acc[j4 * 4 + 3] += w4.w * xv;
        }
    }

    u16* Pb = PB + (size_t)b * CC * NSP + n0 + nl;
    #pragma unroll
    for (int j = 0; j < 48; ++j) {
        int o = ob + j;
        if (o < 64)        Pb[(size_t)o * NSP] = f2bf(acc[j]);            // g cm
        else if (o < 128)  Pb[(size_t)o * NSP] = f2bf(acc[j] * LOG2E);    // theta cm, log2 domain
        else               Tr[o - 128][nl]     = f2bf(acc[j]);            // phi -> LDS
    }
    __syncthreads();
    // phi token-major write
    u16* dst = ph_tm + ((size_t)b * NSP + n0) * 64;
    for (int k = 0; k < 4; ++k) {
        int fi = tid + (k << 8);
        int t = fi >> 4, c4 = (fi & 15) << 2;
        ushort4 v;
        v.x = Tr[c4][t]; v.y = Tr[c4 + 1][t]; v.z = Tr[c4 + 2][t]; v.w = Tr[c4 + 3][t];
        *(ushort4*)(dst + (size_t)t * 64 + c4) = v;
    }
}

// -------------------- Kernel 2: MFMA flash attention ---------------------------
// grid (NSP/16, NB), block 256 = 4 waves. All waves share 16 q rows; wave w owns
// KV quarter [w*1024, (w+1)*1024). Scores in log2 domain (theta pre-scaled).
__global__ __launch_bounds__(256, 4) void attn_kernel(
    const u16* __restrict__ PB, const u16* __restrict__ ph_tm,
    float* __restrict__ y)
{
    const int b    = blockIdx.y;
    const int q0   = blockIdx.x << 4;
    const int tid  = threadIdx.x;
    const int lane = tid & 63;
    const int w    = tid >> 6;       // KV quarter
    const int l15  = lane & 15;
    const int g16  = lane >> 4;

    __shared__ __align__(16) u16 Plds[4][16][72];
    __shared__ float Om[3][16][68];
    __shared__ float Mm[3][16], Lm[3][16];

    const u16* gp  = PB + (size_t)b * CC * NSP;           // g  cm [64][NSP]
    const u16* thc = gp + (size_t)CIC * NSP;              // theta cm [64][NSP] (log2e-scaled)
    const u16* php = ph_tm + (size_t)b * NSP * 64;        // phi tm [NSP][64]

    // Q fragments (once)
    s8bf qa0, qa1;
    const int qtok = q0 + l15;
    #pragma unroll
    for (int j = 0; j < 8; ++j) {
        qa0[j] = (short)thc[(size_t)(g16 * 8 + j) * NSP + qtok];
        qa1[j] = (short)thc[(size_t)(32 + g16 * 8 + j) * NSP + qtok];
    }

    const s8bf ones = {0x3F80, 0x3F80, 0x3F80, 0x3F80, 0x3F80, 0x3F80, 0x3F80, 0x3F80};

    f32x4 Ov[4];
    float mr[4], lr[4];
    #pragma unroll
    for (int c = 0; c < 4; ++c) Ov[c] = (f32x4){0.f, 0.f, 0.f, 0.f};
    #pragma unroll
    for (int r = 0; r < 4; ++r) { mr[r] = -1e30f; lr[r] = 0.f; }

    const u16* kbase = php + ((size_t)((w << 10) + l15) << 6) + (g16 << 3);
    const u16* vbase = gp + (size_t)l15 * NSP + (w << 10) + (g16 << 3);

    for (int t = 0; t < 16; ++t) {
        // ---- QK^T: S strip 16x64 (log2 domain) ----
        const u16* kb = kbase + (t << 12);
        f32x4 sv[4];
        #pragma unroll
        for (int c = 0; c < 4; ++c) {
            sv[c] = (f32x4){0.f, 0.f, 0.f, 0.f};
            s8bf k0 = *(const s8bf*)(kb + (c << 10));
            s8bf k1 = *(const s8bf*)(kb + (c << 10) + 32);
            sv[c] = MFMA(qa0, k0, sv[c]);
            sv[c] = MFMA(qa1, k1, sv[c]);
        }

        // ---- V prefetch into regs (latency hides under softmax) ----
        s8bf vr[8];
        const u16* vb = vbase + (t << 6);
        #pragma unroll
        for (int c = 0; c < 4; ++c) {
            vr[2 * c]     = *(const s8bf*)(vb + ((size_t)c << 16));
            vr[2 * c + 1] = *(const s8bf*)(vb + ((size_t)c << 16) + 32);
        }

        // ---- online softmax (exp2) ----
        float pm[4];
        #pragma unroll
        for (int r = 0; r < 4; ++r)
            pm[r] = fmaxf(fmaxf(sv[0][r], sv[1][r]), fmaxf(sv[2][r], sv[3][r]));
        #pragma unroll
        for (int msk = 1; msk <= 8; msk <<= 1) {
            #pragma unroll
            for (int r = 0; r < 4; ++r)
                pm[r] = fmaxf(pm[r], __shfl_xor(pm[r], msk, 64));
        }
        float esc[4];
        #pragma unroll
        for (int r = 0; r < 4; ++r) {
            float mn = fmaxf(mr[r], pm[r]);
            esc[r] = __builtin_amdgcn_exp2f(mr[r] - mn);
            mr[r] = mn;
        }
        #pragma unroll
        for (int c = 0; c < 4; ++c) {
            #pragma unroll
            for (int r = 0; r < 4; ++r) {
                float p = __builtin_amdgcn_exp2f(sv[c][r] - mr[r]);
                Plds[w][g16 * 4 + r][c * 16 + l15] = f2bf(p);
            }
        }

        // ---- P fragments + row-sum via ones-MFMA ----
        s8bf pa0 = *(const s8bf*)&Plds[w][l15][g16 * 8];
        s8bf pa1 = *(const s8bf*)&Plds[w][l15][32 + g16 * 8];
        f32x4 lsum = (f32x4){0.f, 0.f, 0.f, 0.f};
        lsum = MFMA(pa0, ones, lsum);
        lsum = MFMA(pa1, ones, lsum);
        #pragma unroll
        for (int r = 0; r < 4; ++r)
            lr[r] = lr[r] * esc[r] + lsum[r];

        // ---- PV ----
        #pragma unroll
        for (int c = 0; c < 4; ++c) {
            #pragma unroll
            for (int r = 0; r < 4; ++r)
                Ov[c][r] *= esc[r];
        }
        #pragma unroll
        for (int c = 0; c < 4; ++c) {
            Ov[c] = MFMA(pa0, vr[2 * c], Ov[c]);
            Ov[c] = MFMA(pa1, vr[2 * c + 1], Ov[c]);
        }
    }

    // ---- merge 4 KV quarters ----
    if (w > 0) {
        #pragma unroll
        for (int c = 0; c < 4; ++c) {
            #pragma unroll
            for (int r = 0; r < 4; ++r)
                Om[w - 1][g16 * 4 + r][c * 16 + l15] = Ov[c][r];
        }
        if (l15 == 0) {
            #pragma unroll
            for (int r = 0; r < 4; ++r) { Mm[w - 1][g16 * 4 + r] = mr[r]; Lm[w - 1][g16 * 4 + r] = lr[r]; }
        }
    }
    __syncthreads();
    if (w == 0) {
        #pragma unroll
        for (int p = 0; p < 3; ++p) {
            float e1[4], e2[4];
            #pragma unroll
            for (int r = 0; r < 4; ++r) {
                int row = g16 * 4 + r;
                float m2 = Mm[p][row], l2 = Lm[p][row];
                float ms = fmaxf(mr[r], m2);
                e1[r] = __builtin_amdgcn_exp2f(mr[r] - ms);
                e2[r] = __builtin_amdgcn_exp2f(m2 - ms);
                lr[r] = lr[r] * e1[r] + l2 * e2[r];
                mr[r] = ms;
            }
            #pragma unroll
            for (int c = 0; c < 4; ++c) {
                #pragma unroll
                for (int r = 0; r < 4; ++r)
                    Ov[c][r] = Ov[c][r] * e1[r] + Om[p][g16 * 4 + r][c * 16 + l15] * e2[r];
            }
        }
        float inv[4];
        #pragma unroll
        for (int r = 0; r < 4; ++r) inv[r] = 1.0f / lr[r];
        #pragma unroll
        for (int c = 0; c < 4; ++c) {
            #pragma unroll
            for (int r = 0; r < 4; ++r)
                Om[0][g16 * 4 + r][c * 16 + l15] = Ov[c][r] * inv[r];
        }
    }
    __syncthreads();

    // ---- coalesced y write: 64 ci x 16 q ----
    {
        int ci = tid >> 2, qo = (tid & 3) << 2;
        float4 v;
        v.x = Om[0][qo + 0][ci]; v.y = Om[0][qo + 1][ci];
        v.z = Om[0][qo + 2][ci]; v.w = Om[0][qo + 3][ci];
        *(float4*)&y[((size_t)b * CIC + ci) * NSP + q0 + qo] = v;
    }
}

// -------------------- Kernel 3: W 1x1 conv + fused BN partial sums --------------
__global__ __launch_bounds__(256) void wconv_kernel(
    const float* __restrict__ y, const float* __restrict__ w_w,
    const float* __restrict__ w_b, float* __restrict__ out,
    float* __restrict__ sums)
{
    __shared__ float WsT[CIC][132];
    __shared__ float Ys[CIC][68];

    const int b   = blockIdx.y;
    const int n0  = blockIdx.x * 64;
    const int tid = threadIdx.x;
    const int nl  = tid & 63;
    const int grp = tid >> 6;
    const int c0  = grp * 32;

    for (int j = 0; j < 32; ++j) {
        int idx = tid + (j << 8);
        int c = idx >> 6, ci = idx & 63;
        WsT[ci][c] = w_w[idx];
    }
    for (int k = 0; k < 4; ++k) {
        int fi = tid + (k << 8);
        int ci = fi >> 4, q = (fi & 15) << 2;
        *(float4*)&Ys[ci][q] = *(const float4*)(y + ((size_t)b * CIC + ci) * NSP + n0 + q);
    }
    __syncthreads();

    float acc[32];
    #pragma unroll
    for (int j = 0; j < 32; ++j) acc[j] = 0.f;

    for (int ci = 0; ci < CIC; ++ci) {
        float yv = Ys[ci][nl];
        const float4* wr = (const float4*)&WsT[ci][c0];
        #pragma unroll
        for (int j4 = 0; j4 < 8; ++j4) {
            float4 w4 = wr[j4];
            acc[j4 * 4 + 0] += w4.x * yv;
            acc[j4 * 4 + 1] += w4.y * yv;
            acc[j4 * 4 + 2] += w4.z * yv;
            acc[j4 * 4 + 3] += w4.w * yv;
        }
    }

    #pragma unroll
    for (int j = 0; j < 32; ++j) {
        acc[j] += w_b[c0 + j];
        out[((size_t)b * CC + c0 + j) * NSP + n0 + nl] = acc[j];
    }

    // per-wave (64 tokens) partial sums -> atomics
    #pragma unroll
    for (int j = 0; j < 32; ++j) {
        float v = acc[j], v2 = v * v;
        #pragma unroll
        for (int off = 32; off > 0; off >>= 1) {
            v  += __shfl_down(v, off, 64);
            v2 += __shfl_down(v2, off, 64);
        }
        if (nl == 0) {
            atomicAdd(&sums[c0 + j], v);
            atomicAdd(&sums[CC + c0 + j], v2);
        }
    }
}

// -------------------- Kernel 4: BN finalize + residual (in-place on d_out) ------
__global__ __launch_bounds__(256) void bn_kernel(
    const float* __restrict__ x, const float* __restrict__ sums,
    const float* __restrict__ gamma, const float* __restrict__ beta,
    float* __restrict__ out)
{
    const int i = blockIdx.x * 256 + threadIdx.x;
    const int c = (i >> 10) & (CC - 1);
    float s  = sums[c];
    float ss = sums[CC + c];
    float mean = s * (1.0f / 16384.0f);
    float var  = ss * (1.0f / 16384.0f) - mean * mean;
    float istd = rsqrtf(var + 1e-5f);
    float ga = gamma[c] * istd;
    float be = beta[c] - mean * ga;
    float4 wy = ((const float4*)out)[i];
    float4 xv = ((const float4*)x)[i];
    float4 o;
    o.x = wy.x * ga + be + xv.x;
    o.y = wy.y * ga + be + xv.y;
    o.z = wy.z * ga + be + xv.z;
    o.w = wy.w * ga + be + xv.w;
    ((float4*)out)[i] = o;
}

extern "C" void kernel_launch(void* const* d_in, const int* in_sizes, int n_in,
                              void* d_out, int out_size, void* d_ws, size_t ws_size,
                              hipStream_t stream)
{
    const float* x    = (const float*)d_in[0];
    const float* g_w  = (const float*)d_in[1];
    const float* g_b  = (const float*)d_in[2];
    const float* t_w  = (const float*)d_in[3];
    const float* t_b  = (const float*)d_in[4];
    const float* p_w  = (const float*)d_in[5];
    const float* p_b  = (const float*)d_in[6];
    const float* w_w  = (const float*)d_in[7];
    const float* w_b  = (const float*)d_in[8];
    const float* bn_g = (const float*)d_in[9];
    const float* bn_b = (const float*)d_in[10];
    float* out = (float*)d_out;
    char* ws8  = (char*)d_ws;

    u16*   PB    = (u16*)(ws8 + WSB_PB);
    u16*   PH    = (u16*)(ws8 + WSB_PH);
    float* y     = (float*)(ws8 + WSB_Y);
    float* sums  = (float*)(ws8 + WSB_SUMS);

    hipMemsetAsync(sums, 0, 2 * CC * sizeof(float), stream);
    proj_kernel <<<dim3(NSP / 64, NB), 256, 0, stream>>>(x, g_w, g_b, t_w, t_b, p_w, p_b, PB, PH);
    attn_kernel <<<dim3(NSP / 16, NB), 256, 0, stream>>>(PB, PH, y);
    wconv_kernel<<<dim3(NSP / 64, NB), 256, 0, stream>>>(y, w_w, w_b, out, sums);
    bn_kernel   <<<dim3(2048), 256, 0, stream>>>(x, sums, bn_g, bn_b, out);
}

// Round 4
// 184.751 us; speedup vs baseline: 1.4608x; 1.4608x over previous
//
#include <hip/hip_runtime.h>
#include <math.h>

#define NSP 4096   // H*W
#define CC  128    // channels
#define CIC 64     // inter channels
#define NB  4      // batch
#define LOG2E 1.4426950408889634f

typedef unsigned short u16;
typedef short s8bf __attribute__((ext_vector_type(8)));
typedef float f32x4 __attribute__((ext_vector_type(4)));

#define MFMA(a, b, c) __builtin_amdgcn_mfma_f32_16x16x32_bf16(a, b, c, 0, 0, 0)

// workspace byte offsets
#define WSB_PB    0                               // bf16 [B][128][NSP] (g:0-63, theta*log2e:64-127)
#define WSB_PH    (NB * 128 * NSP * 2)            // bf16 [B][NSP][64] phi token-major
#define WSB_Y     (WSB_PH + NB * NSP * CIC * 2)   // f32 [B][64][NSP]
#define WSB_STATS (WSB_Y + NB * CIC * NSP * 4)    // f32 [2][128] (mean, istd)

__device__ __forceinline__ u16 f2bf(float f) {
    union { float f; unsigned u; } v; v.f = f;
    unsigned r = v.u + 0x7fffu + ((v.u >> 16) & 1u);
    return (u16)(r >> 16);
}

// -------------------- Kernel 1: fused 1x1 projections ---------------------------
// g, theta (pre-scaled by log2e) -> bf16 channel-major; phi -> bf16 token-major.
__global__ __launch_bounds__(256) void proj_kernel(
    const float* __restrict__ x,
    const float* __restrict__ g_w, const float* __restrict__ g_b,
    const float* __restrict__ t_w, const float* __restrict__ t_b,
    const float* __restrict__ p_w, const float* __restrict__ p_b,
    u16* __restrict__ PB, u16* __restrict__ ph_tm)
{
    __shared__ float Wt[CC][196];
    __shared__ float Xs[CC][68];
    __shared__ u16 Tr[64][72];

    const int b   = blockIdx.y;
    const int n0  = blockIdx.x * 64;
    const int tid = threadIdx.x;
    const int nl  = tid & 63;
    const int og  = tid >> 6;
    const int ob  = og * 48;

    for (int j = 0; j < 32; ++j) {
        int idx = tid + (j << 8);
        int o = idx >> 7, c = idx & 127;
        Wt[c][o]       = g_w[idx];
        Wt[c][64 + o]  = t_w[idx];
        Wt[c][128 + o] = p_w[idx];
    }
    const float* xb = x + (size_t)b * CC * NSP + n0;
    for (int k = 0; k < 8; ++k) {
        int fi = tid + (k << 8);
        int c = fi >> 4, q = (fi & 15) << 2;
        *(float4*)&Xs[c][q] = *(const float4*)(xb + (size_t)c * NSP + q);
    }
    __syncthreads();

    float acc[48];
    #pragma unroll
    for (int j = 0; j < 48; ++j) {
        int o = ob + j;
        acc[j] = (o < 64) ? g_b[o] : (o < 128) ? t_b[o - 64] : p_b[o - 128];
    }

    for (int c = 0; c < CC; ++c) {
        float xv = Xs[c][nl];
        const float4* wr = (const float4*)&Wt[c][ob];
        #pragma unroll
        for (int j4 = 0; j4 < 12; ++j4) {
            float4 w4 = wr[j4];
            acc[j4 * 4 + 0] += w4.x * xv;
            acc[j4 * 4 + 1] += w4.y * xv;
            acc[j4 * 4 + 2] += w4.z * xv;
            acc[j4 * 4 + 3] += w4.w * xv;
        }
    }

    u16* Pb = PB + (size_t)b * CC * NSP + n0 + nl;
    #pragma unroll
    for (int j = 0; j < 48; ++j) {
        int o = ob + j;
        if (o < 64)        Pb[(size_t)o * NSP] = f2bf(acc[j]);            // g cm
        else if (o < 128)  Pb[(size_t)o * NSP] = f2bf(acc[j] * LOG2E);    // theta cm, log2 domain
        else               Tr[o - 128][nl]     = f2bf(acc[j]);            // phi -> LDS
    }
    __syncthreads();
    // phi token-major write
    u16* dst = ph_tm + ((size_t)b * NSP + n0) * 64;
    for (int k = 0; k < 4; ++k) {
        int fi = tid + (k << 8);
        int t = fi >> 4, c4 = (fi & 15) << 2;
        ushort4 v;
        v.x = Tr[c4][t]; v.y = Tr[c4 + 1][t]; v.z = Tr[c4 + 2][t]; v.w = Tr[c4 + 3][t];
        *(ushort4*)(dst + (size_t)t * 64 + c4) = v;
    }
}

// -------------------- Kernel 2: MFMA attention, shift-softmax (no max) ----------
// grid (NSP/16, NB), block 256 = 4 waves; wave w owns KV quarter.
// Scores in log2 domain; p = exp2(QK - 32) via MFMA C-init = -32 (free shift).
// No max tracking -> iterations independent -> ILP via unroll-2 + dbuf P strip.
__global__ __launch_bounds__(256, 4) void attn_kernel(
    const u16* __restrict__ PB, const u16* __restrict__ ph_tm,
    float* __restrict__ y)
{
    const int b    = blockIdx.y;
    const int q0   = blockIdx.x << 4;
    const int tid  = threadIdx.x;
    const int lane = tid & 63;
    const int w    = tid >> 6;       // KV quarter
    const int l15  = lane & 15;
    const int g16  = lane >> 4;

    __shared__ __align__(16) u16 Plds[4][2][16][72];
    __shared__ float Om[3][16][68];
    __shared__ float Lm[3][16];

    const u16* gp  = PB + (size_t)b * CC * NSP;           // g  cm [64][NSP]
    const u16* thc = gp + (size_t)CIC * NSP;              // theta cm [64][NSP] (log2e-scaled)
    const u16* php = ph_tm + (size_t)b * NSP * 64;        // phi tm [NSP][64]

    // Q fragments (once)
    s8bf qa0, qa1;
    const int qtok = q0 + l15;
    #pragma unroll
    for (int j = 0; j < 8; ++j) {
        qa0[j] = (short)thc[(size_t)(g16 * 8 + j) * NSP + qtok];
        qa1[j] = (short)thc[(size_t)(32 + g16 * 8 + j) * NSP + qtok];
    }

    const s8bf ones = {0x3F80, 0x3F80, 0x3F80, 0x3F80, 0x3F80, 0x3F80, 0x3F80, 0x3F80};
    const f32x4 cinit = {-32.f, -32.f, -32.f, -32.f};

    f32x4 Ov[4];
    f32x4 lr = (f32x4){0.f, 0.f, 0.f, 0.f};
    #pragma unroll
    for (int c = 0; c < 4; ++c) Ov[c] = (f32x4){0.f, 0.f, 0.f, 0.f};

    const u16* kbase = php + ((size_t)((w << 10) + l15) << 6) + (g16 << 3);
    const u16* vbase = gp + (size_t)l15 * NSP + (w << 10) + (g16 << 3);

    #pragma unroll 2
    for (int t = 0; t < 16; ++t) {
        // ---- QK^T (log2 domain, pre-shifted by -32 via C-init) ----
        const u16* kb = kbase + (t << 12);
        f32x4 sv[4];
        #pragma unroll
        for (int c = 0; c < 4; ++c) {
            s8bf k0 = *(const s8bf*)(kb + (c << 10));
            s8bf k1 = *(const s8bf*)(kb + (c << 10) + 32);
            sv[c] = MFMA(qa0, k0, cinit);
            sv[c] = MFMA(qa1, k1, sv[c]);
        }

        // ---- V prefetch (latency hides under exp/pack) ----
        s8bf vr[8];
        const u16* vb = vbase + (t << 6);
        #pragma unroll
        for (int c = 0; c < 4; ++c) {
            vr[2 * c]     = *(const s8bf*)(vb + ((size_t)c << 16));
            vr[2 * c + 1] = *(const s8bf*)(vb + ((size_t)c << 16) + 32);
        }

        // ---- p = exp2(s) straight to bf16 LDS strip (double-buffered) ----
        u16 (&Pl)[16][72] = Plds[w][t & 1];
        #pragma unroll
        for (int c = 0; c < 4; ++c) {
            #pragma unroll
            for (int r = 0; r < 4; ++r)
                Pl[g16 * 4 + r][c * 16 + l15] = f2bf(__builtin_amdgcn_exp2f(sv[c][r]));
        }

        // ---- P fragments; l via ones-MFMA; PV ----
        s8bf pa0 = *(const s8bf*)&Pl[l15][g16 * 8];
        s8bf pa1 = *(const s8bf*)&Pl[l15][32 + g16 * 8];
        lr = MFMA(pa0, ones, lr);
        lr = MFMA(pa1, ones, lr);
        #pragma unroll
        for (int c = 0; c < 4; ++c) {
            Ov[c] = MFMA(pa0, vr[2 * c], Ov[c]);
            Ov[c] = MFMA(pa1, vr[2 * c + 1], Ov[c]);
        }
    }

    // ---- merge 4 KV quarters: plain sums ----
    if (w > 0) {
        #pragma unroll
        for (int c = 0; c < 4; ++c) {
            #pragma unroll
            for (int r = 0; r < 4; ++r)
                Om[w - 1][g16 * 4 + r][c * 16 + l15] = Ov[c][r];
        }
        if (l15 == 0) {
            #pragma unroll
            for (int r = 0; r < 4; ++r) Lm[w - 1][g16 * 4 + r] = lr[r];
        }
    }
    __syncthreads();
    if (w == 0) {
        #pragma unroll
        for (int p = 0; p < 3; ++p) {
            #pragma unroll
            for (int r = 0; r < 4; ++r) lr[r] += Lm[p][g16 * 4 + r];
            #pragma unroll
            for (int c = 0; c < 4; ++c) {
                #pragma unroll
                for (int r = 0; r < 4; ++r)
                    Ov[c][r] += Om[p][g16 * 4 + r][c * 16 + l15];
            }
        }
        float inv[4];
        #pragma unroll
        for (int r = 0; r < 4; ++r) inv[r] = 1.0f / lr[r];
        #pragma unroll
        for (int c = 0; c < 4; ++c) {
            #pragma unroll
            for (int r = 0; r < 4; ++r)
                Om[0][g16 * 4 + r][c * 16 + l15] = Ov[c][r] * inv[r];
        }
    }
    __syncthreads();

    // ---- coalesced y write: 64 ci x 16 q ----
    {
        int ci = tid >> 2, qo = (tid & 3) << 2;
        float4 v;
        v.x = Om[0][qo + 0][ci]; v.y = Om[0][qo + 1][ci];
        v.z = Om[0][qo + 2][ci]; v.w = Om[0][qo + 3][ci];
        *(float4*)&y[((size_t)b * CIC + ci) * NSP + q0 + qo] = v;
    }
}

// -------------------- Kernel 3: W 1x1 conv -> w_y into d_out --------------------
__global__ __launch_bounds__(256) void wconv_kernel(
    const float* __restrict__ y, const float* __restrict__ w_w,
    const float* __restrict__ w_b, float* __restrict__ out)
{
    __shared__ float WsT[CIC][132];
    __shared__ float Ys[CIC][68];

    const int b   = blockIdx.y;
    const int n0  = blockIdx.x * 64;
    const int tid = threadIdx.x;
    const int nl  = tid & 63;
    const int grp = tid >> 6;
    const int c0  = grp * 32;

    for (int j = 0; j < 32; ++j) {
        int idx = tid + (j << 8);
        int c = idx >> 6, ci = idx & 63;
        WsT[ci][c] = w_w[idx];
    }
    for (int k = 0; k < 4; ++k) {
        int fi = tid + (k << 8);
        int ci = fi >> 4, q = (fi & 15) << 2;
        *(float4*)&Ys[ci][q] = *(const float4*)(y + ((size_t)b * CIC + ci) * NSP + n0 + q);
    }
    __syncthreads();

    float acc[32];
    #pragma unroll
    for (int j = 0; j < 32; ++j) acc[j] = 0.f;

    for (int ci = 0; ci < CIC; ++ci) {
        float yv = Ys[ci][nl];
        const float4* wr = (const float4*)&WsT[ci][c0];
        #pragma unroll
        for (int j4 = 0; j4 < 8; ++j4) {
            float4 w4 = wr[j4];
            acc[j4 * 4 + 0] += w4.x * yv;
            acc[j4 * 4 + 1] += w4.y * yv;
            acc[j4 * 4 + 2] += w4.z * yv;
            acc[j4 * 4 + 3] += w4.w * yv;
        }
    }

    #pragma unroll
    for (int j = 0; j < 32; ++j)
        out[((size_t)b * CC + c0 + j) * NSP + n0 + nl] = acc[j] + w_b[c0 + j];
}

// -------------------- Kernel 4: per-channel batch stats -------------------------
__global__ __launch_bounds__(256) void stats_kernel(
    const float* __restrict__ wy, float* __restrict__ stats)
{
    const int c   = blockIdx.x;
    const int tid = threadIdx.x;
    double s = 0.0, ss = 0.0;
    for (int i = tid; i < NB * NSP; i += 256) {
        int b = i >> 12, n = i & (NSP - 1);
        float v = wy[((size_t)b * CC + c) * NSP + n];
        s += v; ss += (double)v * v;
    }
    #pragma unroll
    for (int off = 32; off > 0; off >>= 1) {
        s  += __shfl_down(s, off);
        ss += __shfl_down(ss, off);
    }
    __shared__ double sred[4], ssred[4];
    const int wid = tid >> 6, lane = tid & 63;
    if (lane == 0) { sred[wid] = s; ssred[wid] = ss; }
    __syncthreads();
    if (tid == 0) {
        double st  = sred[0] + sred[1] + sred[2] + sred[3];
        double sst = ssred[0] + ssred[1] + ssred[2] + ssred[3];
        double mean = st / 16384.0;
        double var  = sst / 16384.0 - mean * mean;
        stats[c]      = (float)mean;
        stats[CC + c] = (float)(1.0 / sqrt(var + 1e-5));
    }
}

// -------------------- Kernel 5: BN + residual (in-place on d_out) ---------------
__global__ __launch_bounds__(256) void bn_kernel(
    const float* __restrict__ x, const float* __restrict__ stats,
    const float* __restrict__ gamma, const float* __restrict__ beta,
    float* __restrict__ out)
{
    const int i = blockIdx.x * 256 + threadIdx.x;
    const int c = (i >> 10) & (CC - 1);
    float mean = stats[c];
    float istd = stats[CC + c];
    float ga = gamma[c] * istd;
    float be = beta[c] - mean * ga;
    float4 wy = ((const float4*)out)[i];
    float4 xv = ((const float4*)x)[i];
    float4 o;
    o.x = wy.x * ga + be + xv.x;
    o.y = wy.y * ga + be + xv.y;
    o.z = wy.z * ga + be + xv.z;
    o.w = wy.w * ga + be + xv.w;
    ((float4*)out)[i] = o;
}

extern "C" void kernel_launch(void* const* d_in, const int* in_sizes, int n_in,
                              void* d_out, int out_size, void* d_ws, size_t ws_size,
                              hipStream_t stream)
{
    const float* x    = (const float*)d_in[0];
    const float* g_w  = (const float*)d_in[1];
    const float* g_b  = (const float*)d_in[2];
    const float* t_w  = (const float*)d_in[3];
    const float* t_b  = (const float*)d_in[4];
    const float* p_w  = (const float*)d_in[5];
    const float* p_b  = (const float*)d_in[6];
    const float* w_w  = (const float*)d_in[7];
    const float* w_b  = (const float*)d_in[8];
    const float* bn_g = (const float*)d_in[9];
    const float* bn_b = (const float*)d_in[10];
    float* out = (float*)d_out;
    char* ws8  = (char*)d_ws;

    u16*   PB    = (u16*)(ws8 + WSB_PB);
    u16*   PH    = (u16*)(ws8 + WSB_PH);
    float* y     = (float*)(ws8 + WSB_Y);
    float* stats = (float*)(ws8 + WSB_STATS);

    proj_kernel <<<dim3(NSP / 64, NB), 256, 0, stream>>>(x, g_w, g_b, t_w, t_b, p_w, p_b, PB, PH);
    attn_kernel <<<dim3(NSP / 16, NB), 256, 0, stream>>>(PB, PH, y);
    wconv_kernel<<<dim3(NSP / 64, NB), 256, 0, stream>>>(y, w_w, w_b, out);
    stats_kernel<<<dim3(CC), 256, 0, stream>>>(out, stats);
    bn_kernel   <<<dim3(2048), 256, 0, stream>>>(x, stats, bn_g, bn_b, out);
}

// Round 5
// 100.146 us; speedup vs baseline: 2.6949x; 1.8448x over previous
//
#include <hip/hip_runtime.h>
#include <math.h>

#define NSP 4096   // H*W
#define CC  128    // channels
#define CIC 64     // inter channels
#define NB  4      // batch
#define LOG2E 1.4426950408889634f

typedef unsigned short u16;
typedef short s8bf __attribute__((ext_vector_type(8)));
typedef float f32x4 __attribute__((ext_vector_type(4)));

#define MFMA(a, b, c) __builtin_amdgcn_mfma_f32_16x16x32_bf16(a, b, c, 0, 0, 0)

// workspace byte offsets
#define WSB_PB    0                               // bf16 [B][128][NSP] (g:0-63, theta*log2e:64-127)
#define WSB_PH    (NB * 128 * NSP * 2)            // bf16 [B][NSP][64] phi token-major
#define WSB_Y     (WSB_PH + NB * NSP * CIC * 2)   // f32 [B][64][NSP]
#define WSB_STATS (WSB_Y + NB * CIC * NSP * 4)    // f32 [2][128] (mean, istd)

__device__ __forceinline__ u16 f2bf(float f) {
    union { float f; unsigned u; } v; v.f = f;
    unsigned r = v.u + 0x7fffu + ((v.u >> 16) & 1u);
    return (u16)(r >> 16);
}

// -------------------- Kernel 1: fused 1x1 projections ---------------------------
// g, theta (pre-scaled by log2e) -> bf16 channel-major; phi -> bf16 token-major.
__global__ __launch_bounds__(256) void proj_kernel(
    const float* __restrict__ x,
    const float* __restrict__ g_w, const float* __restrict__ g_b,
    const float* __restrict__ t_w, const float* __restrict__ t_b,
    const float* __restrict__ p_w, const float* __restrict__ p_b,
    u16* __restrict__ PB, u16* __restrict__ ph_tm)
{
    __shared__ float Wt[CC][196];
    __shared__ float Xs[CC][68];
    __shared__ u16 Tr[64][72];

    const int b   = blockIdx.y;
    const int n0  = blockIdx.x * 64;
    const int tid = threadIdx.x;
    const int nl  = tid & 63;
    const int og  = tid >> 6;
    const int ob  = og * 48;

    for (int j = 0; j < 32; ++j) {
        int idx = tid + (j << 8);
        int o = idx >> 7, c = idx & 127;
        Wt[c][o]       = g_w[idx];
        Wt[c][64 + o]  = t_w[idx];
        Wt[c][128 + o] = p_w[idx];
    }
    const float* xb = x + (size_t)b * CC * NSP + n0;
    for (int k = 0; k < 8; ++k) {
        int fi = tid + (k << 8);
        int c = fi >> 4, q = (fi & 15) << 2;
        *(float4*)&Xs[c][q] = *(const float4*)(xb + (size_t)c * NSP + q);
    }
    __syncthreads();

    float acc[48];
    #pragma unroll
    for (int j = 0; j < 48; ++j) {
        int o = ob + j;
        acc[j] = (o < 64) ? g_b[o] : (o < 128) ? t_b[o - 64] : p_b[o - 128];
    }

    for (int c = 0; c < CC; ++c) {
        float xv = Xs[c][nl];
        const float4* wr = (const float4*)&Wt[c][ob];
        #pragma unroll
        for (int j4 = 0; j4 < 12; ++j4) {
            float4 w4 = wr[j4];
            acc[j4 * 4 + 0] += w4.x * xv;
            acc[j4 * 4 + 1] += w4.y * xv;
            acc[j4 * 4 + 2] += w4.z * xv;
            acc[j4 * 4 + 3] += w4.w * xv;
        }
    }

    u16* Pb = PB + (size_t)b * CC * NSP + n0 + nl;
    #pragma unroll
    for (int j = 0; j < 48; ++j) {
        int o = ob + j;
        if (o < 64)        Pb[(size_t)o * NSP] = f2bf(acc[j]);            // g cm
        else if (o < 128)  Pb[(size_t)o * NSP] = f2bf(acc[j] * LOG2E);    // theta cm, log2 domain
        else               Tr[o - 128][nl]     = f2bf(acc[j]);            // phi -> LDS
    }
    __syncthreads();
    // phi token-major write
    u16* dst = ph_tm + ((size_t)b * NSP + n0) * 64;
    for (int k = 0; k < 4; ++k) {
        int fi = tid + (k << 8);
        int t = fi >> 4, c4 = (fi & 15) << 2;
        ushort4 v;
        v.x = Tr[c4][t]; v.y = Tr[c4 + 1][t]; v.z = Tr[c4 + 2][t]; v.w = Tr[c4 + 3][t];
        *(ushort4*)(dst + (size_t)t * 64 + c4) = v;
    }
}

// -------------------- Kernel 2: MFMA attention, LDS-staged K/V ------------------
// grid (NSP/64, NB), block 512 = 8 waves. Wave w: q-strip s=w&3 (16 rows),
// KV-half h=w>>2 (2048 tokens, 32 tiles of 64). K/V tiles staged to LDS
// cooperatively (coalesced float4 -> swizzled ds_write_b128), double-buffered,
// 1 barrier/iter. Shift-softmax (no max): p = exp2(QK - 32) via MFMA C-init.
__global__ __launch_bounds__(512, 2) void attn_kernel(
    const u16* __restrict__ PB, const u16* __restrict__ ph_tm,
    float* __restrict__ y)
{
    const int b    = blockIdx.y;
    const int q0   = blockIdx.x << 6;
    const int tid  = threadIdx.x;
    const int lane = tid & 63;
    const int w    = tid >> 6;       // 0..7
    const int s    = w & 3;          // q strip
    const int h    = w >> 2;         // kv half
    const int l15  = lane & 15;
    const int g16  = lane >> 4;

    // [dbuf][K=0/V=1][half][64 rows x 128B, XOR-swizzled]
    __shared__ __align__(16) char KV[2][2][2][8192];
    __shared__ __align__(16) u16 Plds[8][16][72];
    __shared__ float Om[4][16][68];
    __shared__ float Lm[4][16];

    const u16* gp  = PB + (size_t)b * CC * NSP;           // g  cm [64][NSP]
    const u16* thc = gp + (size_t)CIC * NSP;              // theta cm (log2e-scaled)
    const u16* php = ph_tm + (size_t)b * NSP * 64;        // phi tm [NSP][64]

    // staging role: row = tid>>3 (0..63), 16B chunk = tid&7; swizzled LDS dest
    const int srow = tid >> 3;
    const int scol = tid & 7;
    const int ldst = srow * 128 + (((scol ^ (srow & 7)) & 7) << 4);

    float4 rK0, rK1, rV0, rV1;
    auto load_t = [&](int t) {
        const int m0 = t << 6;
        rK0 = *(const float4*)(php + ((size_t)(       m0 + srow) << 6) + (scol << 3));
        rK1 = *(const float4*)(php + ((size_t)(2048 + m0 + srow) << 6) + (scol << 3));
        rV0 = *(const float4*)(gp + (size_t)srow * NSP +        m0 + (scol << 3));
        rV1 = *(const float4*)(gp + (size_t)srow * NSP + 2048 + m0 + (scol << 3));
    };
    auto write_t = [&](int buf) {
        *(float4*)(&KV[buf][0][0][0] + ldst) = rK0;
        *(float4*)(&KV[buf][0][1][0] + ldst) = rK1;
        *(float4*)(&KV[buf][1][0][0] + ldst) = rV0;
        *(float4*)(&KV[buf][1][1][0] + ldst) = rV1;
    };

    // Q fragments (once): 16 scalar gathers from channel-major theta
    s8bf qa0, qa1;
    const int qtok = q0 + s * 16 + l15;
    #pragma unroll
    for (int j = 0; j < 8; ++j) {
        qa0[j] = (short)thc[(size_t)(g16 * 8 + j) * NSP + qtok];
        qa1[j] = (short)thc[(size_t)(32 + g16 * 8 + j) * NSP + qtok];
    }

    const s8bf ones = {0x3F80, 0x3F80, 0x3F80, 0x3F80, 0x3F80, 0x3F80, 0x3F80, 0x3F80};
    const f32x4 cinit = {-32.f, -32.f, -32.f, -32.f};

    f32x4 Ov[4];
    f32x4 lr = (f32x4){0.f, 0.f, 0.f, 0.f};
    #pragma unroll
    for (int c = 0; c < 4; ++c) Ov[c] = (f32x4){0.f, 0.f, 0.f, 0.f};

    load_t(0); write_t(0); load_t(1);
    __syncthreads();

    for (int t = 0; t < 32; ++t) {
        const int buf = t & 1;
        const char* Kb = &KV[buf][0][h][0];
        const char* Vb = &KV[buf][1][h][0];

        // ---- QK^T from swizzled LDS K tile ----
        f32x4 sv[4];
        __builtin_amdgcn_s_setprio(1);
        #pragma unroll
        for (int c = 0; c < 4; ++c) {
            const int tok = c * 16 + l15;
            const int sx  = (tok & 7) << 4;
            s8bf k0 = *(const s8bf*)(Kb + tok * 128 + ((g16 * 16)      ^ sx));
            s8bf k1 = *(const s8bf*)(Kb + tok * 128 + ((g16 * 16 + 64) ^ sx));
            sv[c] = MFMA(qa0, k0, cinit);
            sv[c] = MFMA(qa1, k1, sv[c]);
        }
        __builtin_amdgcn_s_setprio(0);

        // ---- p = exp2(s) -> bf16 P strip (wave-private) ----
        u16 (&Pl)[16][72] = Plds[w];
        #pragma unroll
        for (int c = 0; c < 4; ++c) {
            #pragma unroll
            for (int r = 0; r < 4; ++r)
                Pl[g16 * 4 + r][c * 16 + l15] = f2bf(__builtin_amdgcn_exp2f(sv[c][r]));
        }

        // ---- P fragments; l via ones-MFMA; PV from swizzled LDS V tile ----
        s8bf pa0 = *(const s8bf*)&Pl[l15][g16 * 8];
        s8bf pa1 = *(const s8bf*)&Pl[l15][32 + g16 * 8];
        __builtin_amdgcn_s_setprio(1);
        lr = MFMA(pa0, ones, lr);
        lr = MFMA(pa1, ones, lr);
        #pragma unroll
        for (int c = 0; c < 4; ++c) {
            const int ci = c * 16 + l15;
            const int sx = (ci & 7) << 4;
            s8bf v0 = *(const s8bf*)(Vb + ci * 128 + ((g16 * 16)      ^ sx));
            s8bf v1 = *(const s8bf*)(Vb + ci * 128 + ((g16 * 16 + 64) ^ sx));
            Ov[c] = MFMA(pa0, v0, Ov[c]);
            Ov[c] = MFMA(pa1, v1, Ov[c]);
        }
        __builtin_amdgcn_s_setprio(0);

        // ---- stage next tile: swizzled LDS writes, then prefetch t+2 ----
        if (t < 31) {
            write_t(buf ^ 1);
            if (t < 30) load_t(t + 2);
        }
        __syncthreads();
    }

    // ---- merge the 2 KV halves (plain adds; no max state) ----
    if (h == 1) {
        #pragma unroll
        for (int c = 0; c < 4; ++c) {
            #pragma unroll
            for (int r = 0; r < 4; ++r)
                Om[s][g16 * 4 + r][c * 16 + l15] = Ov[c][r];
        }
        if (l15 == 0) {
            #pragma unroll
            for (int r = 0; r < 4; ++r) Lm[s][g16 * 4 + r] = lr[r];
        }
    }
    __syncthreads();
    if (h == 0) {
        float inv[4];
        #pragma unroll
        for (int r = 0; r < 4; ++r) inv[r] = 1.0f / (lr[r] + Lm[s][g16 * 4 + r]);
        #pragma unroll
        for (int c = 0; c < 4; ++c) {
            #pragma unroll
            for (int r = 0; r < 4; ++r) {
                int row = g16 * 4 + r, col = c * 16 + l15;
                Om[s][row][col] = (Ov[c][r] + Om[s][row][col]) * inv[r];
            }
        }
    }
    __syncthreads();

    // ---- coalesced y write: 64 ci x 64 q ----
    #pragma unroll
    for (int k = 0; k < 2; ++k) {
        int idx = tid + (k << 9);        // 0..1023
        int ci = idx >> 4, q4 = (idx & 15) << 2;
        int ss = q4 >> 4, r0 = q4 & 15;
        float4 v;
        v.x = Om[ss][r0][ci]; v.y = Om[ss][r0 + 1][ci];
        v.z = Om[ss][r0 + 2][ci]; v.w = Om[ss][r0 + 3][ci];
        *(float4*)&y[((size_t)b * CIC + ci) * NSP + q0 + q4] = v;
    }
}

// -------------------- Kernel 3: W 1x1 conv -> w_y into d_out --------------------
__global__ __launch_bounds__(256) void wconv_kernel(
    const float* __restrict__ y, const float* __restrict__ w_w,
    const float* __restrict__ w_b, float* __restrict__ out)
{
    __shared__ float WsT[CIC][132];
    __shared__ float Ys[CIC][68];

    const int b   = blockIdx.y;
    const int n0  = blockIdx.x * 64;
    const int tid = threadIdx.x;
    const int nl  = tid & 63;
    const int grp = tid >> 6;
    const int c0  = grp * 32;

    for (int j = 0; j < 32; ++j) {
        int idx = tid + (j << 8);
        int c = idx >> 6, ci = idx & 63;
        WsT[ci][c] = w_w[idx];
    }
    for (int k = 0; k < 4; ++k) {
        int fi = tid + (k << 8);
        int ci = fi >> 4, q = (fi & 15) << 2;
        *(float4*)&Ys[ci][q] = *(const float4*)(y + ((size_t)b * CIC + ci) * NSP + n0 + q);
    }
    __syncthreads();

    float acc[32];
    #pragma unroll
    for (int j = 0; j < 32; ++j) acc[j] = 0.f;

    for (int ci = 0; ci < CIC; ++ci) {
        float yv = Ys[ci][nl];
        const float4* wr = (const float4*)&WsT[ci][c0];
        #pragma unroll
        for (int j4 = 0; j4 < 8; ++j4) {
            float4 w4 = wr[j4];
            acc[j4 * 4 + 0] += w4.x * yv;
            acc[j4 * 4 + 1] += w4.y * yv;
            acc[j4 * 4 + 2] += w4.z * yv;
            acc[j4 * 4 + 3] += w4.w * yv;
        }
    }

    #pragma unroll
    for (int j = 0; j < 32; ++j)
        out[((size_t)b * CC + c0 + j) * NSP + n0 + nl] = acc[j] + w_b[c0 + j];
}

// -------------------- Kernel 4: per-channel batch stats -------------------------
__global__ __launch_bounds__(256) void stats_kernel(
    const float* __restrict__ wy, float* __restrict__ stats)
{
    const int c   = blockIdx.x;
    const int tid = threadIdx.x;
    double s = 0.0, ss = 0.0;
    for (int i = tid; i < NB * NSP; i += 256) {
        int b = i >> 12, n = i & (NSP - 1);
        float v = wy[((size_t)b * CC + c) * NSP + n];
        s += v; ss += (double)v * v;
    }
    #pragma unroll
    for (int off = 32; off > 0; off >>= 1) {
        s  += __shfl_down(s, off);
        ss += __shfl_down(ss, off);
    }
    __shared__ double sred[4], ssred[4];
    const int wid = tid >> 6, lane = tid & 63;
    if (lane == 0) { sred[wid] = s; ssred[wid] = ss; }
    __syncthreads();
    if (tid == 0) {
        double st  = sred[0] + sred[1] + sred[2] + sred[3];
        double sst = ssred[0] + ssred[1] + ssred[2] + ssred[3];
        double mean = st / 16384.0;
        double var  = sst / 16384.0 - mean * mean;
        stats[c]      = (float)mean;
        stats[CC + c] = (float)(1.0 / sqrt(var + 1e-5));
    }
}

// -------------------- Kernel 5: BN + residual (in-place on d_out) ---------------
__global__ __launch_bounds__(256) void bn_kernel(
    const float* __restrict__ x, const float* __restrict__ stats,
    const float* __restrict__ gamma, const float* __restrict__ beta,
    float* __restrict__ out)
{
    const int i = blockIdx.x * 256 + threadIdx.x;
    const int c = (i >> 10) & (CC - 1);
    float mean = stats[c];
    float istd = stats[CC + c];
    float ga = gamma[c] * istd;
    float be = beta[c] - mean * ga;
    float4 wy = ((const float4*)out)[i];
    float4 xv = ((const float4*)x)[i];
    float4 o;
    o.x = wy.x * ga + be + xv.x;
    o.y = wy.y * ga + be + xv.y;
    o.z = wy.z * ga + be + xv.z;
    o.w = wy.w * ga + be + xv.w;
    ((float4*)out)[i] = o;
}

extern "C" void kernel_launch(void* const* d_in, const int* in_sizes, int n_in,
                              void* d_out, int out_size, void* d_ws, size_t ws_size,
                              hipStream_t stream)
{
    const float* x    = (const float*)d_in[0];
    const float* g_w  = (const float*)d_in[1];
    const float* g_b  = (const float*)d_in[2];
    const float* t_w  = (const float*)d_in[3];
    const float* t_b  = (const float*)d_in[4];
    const float* p_w  = (const float*)d_in[5];
    const float* p_b  = (const float*)d_in[6];
    const float* w_w  = (const float*)d_in[7];
    const float* w_b  = (const float*)d_in[8];
    const float* bn_g = (const float*)d_in[9];
    const float* bn_b = (const float*)d_in[10];
    float* out = (float*)d_out;
    char* ws8  = (char*)d_ws;

    u16*   PB    = (u16*)(ws8 + WSB_PB);
    u16*   PH    = (u16*)(ws8 + WSB_PH);
    float* y     = (float*)(ws8 + WSB_Y);
    float* stats = (float*)(ws8 + WSB_STATS);

    proj_kernel <<<dim3(NSP / 64, NB), 256, 0, stream>>>(x, g_w, g_b, t_w, t_b, p_w, p_b, PB, PH);
    attn_kernel <<<dim3(NSP / 64, NB), 512, 0, stream>>>(PB, PH, y);
    wconv_kernel<<<dim3(NSP / 64, NB), 256, 0, stream>>>(y, w_w, w_b, out);
    stats_kernel<<<dim3(CC), 256, 0, stream>>>(out, stats);
    bn_kernel   <<<dim3(2048), 256, 0, stream>>>(x, stats, bn_g, bn_b, out);
}